// Round 8
// baseline (3008.516 us; speedup 1.0000x reference)
//
#include <hip/hip_runtime.h>
#include <hip/hip_bf16.h>
#include <math.h>

#define B_ 256
#define L_ 512
#define V_ 256
#define E_ 256
#define H_ 1024

typedef float  f32x4  __attribute__((ext_vector_type(4)));
typedef short  bf16x8 __attribute__((ext_vector_type(8)));
typedef unsigned int u32;
typedef unsigned int u32x2 __attribute__((ext_vector_type(2)));
typedef unsigned int u32x4 __attribute__((ext_vector_type(4)));

static __device__ __forceinline__ ushort f2bf(float v) {
    __hip_bfloat16 b = __float2bfloat16(v);
    return *reinterpret_cast<ushort*>(&b);
}

// fast tanh: 1 - 2/(exp(2z)+1); exact limits, ~1e-7 rel err
static __device__ __forceinline__ float ftanh(float z) {
    float e = __expf(2.f * z);
    return 1.f - 2.f / (e + 1.f);
}

// ---------- prep: transpose f32 [R][C] -> bf16 [C][R] ----------
__global__ void k_transpose_bf16(const float* __restrict__ in, ushort* __restrict__ out,
                                 int R, int C) {
    __shared__ float tile[64][65];
    int bx = blockIdx.x, by = blockIdx.y;
    int tid = threadIdx.x;
    int g = tid >> 6, l = tid & 63;
    for (int i = 0; i < 16; ++i) {
        int r = g * 16 + i;
        tile[r][l] = in[(size_t)(by * 64 + r) * C + bx * 64 + l];
    }
    __syncthreads();
    for (int i = 0; i < 16; ++i) {
        int c = g * 16 + i;
        out[(size_t)(bx * 64 + c) * R + by * 64 + l] = f2bf(tile[l][c]);
    }
}

// ---------- prep: zero u32 buffer (ring tag invalidation, every launch) ----------
__global__ void k_zero(u32* __restrict__ p, int n) {
    int i = blockIdx.x * blockDim.x + threadIdx.x;
    if (i < n) p[i] = 0u;
}

// ---------- prep: pack H_0 as tagged u32 (tag 0) into ring slot 0 ----------
__global__ void k_pack0(const float* __restrict__ hid, u32* __restrict__ ring, int n) {
    int i = blockIdx.x * blockDim.x + threadIdx.x;
    if (i < n) ring[i] = ((u32)f2bf(hid[i]) << 16) | 0u;
}

// ---------- prep: proj[t][h] = sum_e emb[t][e] * W_e[e][h]  (f32) ----------
__global__ void k_proj(const float* __restrict__ emb, const float* __restrict__ We,
                       float* __restrict__ proj) {
    __shared__ float er[E_];
    int t = blockIdx.x;
    int h = blockIdx.y * 256 + threadIdx.x;
    er[threadIdx.x] = emb[t * E_ + threadIdx.x];
    __syncthreads();
    float acc = 0.f;
#pragma unroll 8
    for (int e = 0; e < E_; ++e) acc += er[e] * We[(size_t)e * H_ + h];
    proj[(size_t)t * H_ + h] = acc;
}

// ---------- persistent scan kernel: tagged-data exchange, no flags ----------
// 256 blocks, 1/CU (134KB LDS). Block (rg=bid&7, cg=bid>>3) owns h rows
// [rg*32,+32) x cols [cg*32,+32). h transported as u32 (bf16<<16 | step_tag):
// the consumer's staging loop loads + validates tags (retry until all == s).
// No producer drain, no flag stores, no separate poll. 2 parity ring slots are
// safe: a producer writes H_{s+1} only after validating ALL of H_s, which proves
// every group peer finished reading H_{s-1} (the slot being overwritten).
// Ring re-zeroed every launch so stale tags from a prior replay never validate.
__global__ __launch_bounds__(256, 1) void k_scan(
    const int* __restrict__ x, const float* __restrict__ proj,
    const ushort* __restrict__ WhT, const ushort* __restrict__ WoT,
    u32* __restrict__ ring, float* __restrict__ logits,
    float* __restrict__ final_h)
{
    __shared__ ushort lds_w[32 * 1024];   // W_h^T cols slice, swizzled (64KB), persistent
    __shared__ ushort panel[32 * 1024];   // H_s rows slice, swizzled bf16 (64KB)
    __shared__ float  red[256 * 5];       // B-phase reduce, stride-5 (5KB)

    int tid = threadIdx.x;
    int w = tid >> 6, lane = tid & 63;
    int l15 = lane & 15, l4 = lane >> 4;
    int bid = blockIdx.x;
    int rg = bid & 7;             // row-group
    int cg = bid >> 3;            // 0..31 col-group
    int r0 = rg * 32, c0 = cg * 32;

    // --- preload W slice once (read-only; drained by first staging vmcnt(0))
    {
        const char* wsrc = (const char*)(WhT + (size_t)c0 * H_);
        char* wd = (char*)lds_w;
        for (int i = 0; i < 16; ++i) {
            int chunk = (w * 16 + i) * 1024;
            int o = chunk + lane * 16;
            int row = o >> 11, b = o & 2047;
            int so = row * 2048 + (b ^ ((row & 7) << 4));
            __builtin_amdgcn_global_load_lds(
                (const __attribute__((address_space(1))) void*)(wsrc + so),
                (__attribute__((address_space(3))) void*)(wd + chunk), 16, 0, 0);
        }
    }

    // A-phase constants: wave quadrant (a,bc) of the 32x32 tile
    int a = w >> 1, bc = w & 1;
    int arow = a * 16 + l15;
    int brow = bc * 16 + l15;
    const char* ha = (const char*)panel + arow * 2048;
    const char* wa = (const char*)lds_w + brow * 2048;
    int as = (arow & 7) << 4, bs = (brow & 7) << 4;
    int gcol = c0 + bc * 16 + l15;

    // B-phase constants: logits rows r0+(cg&1)*16..+16, vocab cols (cg>>1)*16..+16
    int lrg = cg & 1, vcol0 = (cg >> 1) * 16;
    int srow = lrg * 16 + l15;
    const char* hbp = (const char*)panel + srow * 2048;
    int hs2 = (srow & 7) << 4;
    const ushort* wo = WoT + (size_t)(vcol0 + l15) * H_;

    for (int s = 0; s <= L_; ++s) {
        // --- prefetch x/proj gathers for A(s) (read-only, cached)
        float pv[4];
        if (s < L_) {
#pragma unroll
            for (int j = 0; j < 4; ++j) {
                int grow = r0 + a * 16 + l4 * 4 + j;
                pv[j] = proj[(size_t)x[grow * L_ + s] * H_ + gcol];
            }
        }

        // --- stage H_s with tag validation (the stage IS the poll)
        {
            const u32 tag = (u32)s;
            const char* base = (const char*)(ring + (size_t)(s & 1) * B_ * H_
                                             + (size_t)r0 * H_);
            for (int c = 0; c < 2; ++c) {
                u32x4 tv[16];
                bool ok;
                do {
#pragma unroll
                    for (int i = 0; i < 16; ++i) {
                        const char* p = base + (size_t)(c * 16 + i) * 4096 + tid * 16;
                        asm volatile("global_load_dwordx4 %0, %1, off sc0 sc1"
                                     : "=v"(tv[i]) : "v"(p) : "memory");
                    }
                    asm volatile("s_waitcnt vmcnt(0)" ::: "memory");
                    __builtin_amdgcn_sched_barrier(0);   // rule #18: tag cmps are reg-only
                    ok = true;
#pragma unroll
                    for (int i = 0; i < 16; ++i)
#pragma unroll
                        for (int j = 0; j < 4; ++j)
                            ok = ok & ((tv[i][j] & 0xFFFFu) == tag);
                } while (!ok);
                // pack 4 tagged u32 -> 4 bf16 (8B), swizzled ds_write
#pragma unroll
                for (int i = 0; i < 16; ++i) {
                    u32 lo = (tv[i][1] & 0xFFFF0000u) | (tv[i][0] >> 16);
                    u32 hi = (tv[i][3] & 0xFFFF0000u) | (tv[i][2] >> 16);
                    int row = c * 16 + i;
                    int b = tid * 8;                      // byte offset along the row
                    int o = row * 2048 + (b ^ ((row & 7) << 4));
                    *(u32x2*)((char*)panel + o) = (u32x2){lo, hi};
                }
            }
        }
        __syncthreads();   // panel = H_s (bf16, swizzled)

        // --- A phase: H_{s+1} tile = tanh(pv + H_s @ W_h); store tagged u32
        if (s < L_) {
            f32x4 acc0 = {0.f, 0.f, 0.f, 0.f};
            f32x4 acc1 = {0.f, 0.f, 0.f, 0.f};
#pragma unroll
            for (int kk = 0; kk < 32; kk += 2) {
                int kb0 = (kk * 32 + l4 * 8) * 2;
                int kb1 = ((kk + 1) * 32 + l4 * 8) * 2;
                bf16x8 af0 = *(const bf16x8*)(ha + (kb0 ^ as));
                bf16x8 bf0 = *(const bf16x8*)(wa + (kb0 ^ bs));
                bf16x8 af1 = *(const bf16x8*)(ha + (kb1 ^ as));
                bf16x8 bf1 = *(const bf16x8*)(wa + (kb1 ^ bs));
                acc0 = __builtin_amdgcn_mfma_f32_16x16x32_bf16(af0, bf0, acc0, 0, 0, 0);
                acc1 = __builtin_amdgcn_mfma_f32_16x16x32_bf16(af1, bf1, acc1, 0, 0, 0);
            }
            u32* rdst = ring + (size_t)((s + 1) & 1) * B_ * H_;
#pragma unroll
            for (int j = 0; j < 4; ++j) {
                int grow = r0 + a * 16 + l4 * 4 + j;
                float hv = ftanh((acc0[j] + acc1[j]) + pv[j]);
                u32 word = ((u32)f2bf(hv) << 16) | (u32)(s + 1);
                u32* dst = rdst + (size_t)grow * H_ + gcol;
                asm volatile("global_store_dword %0, %1, off sc0 sc1"
                             :: "v"(dst), "v"(word) : "memory");
                if (s == L_ - 1) final_h[(size_t)grow * H_ + gcol] = hv;
            }
            // no drain, no flag: consumers validate every word themselves
        }

        // --- B phase: logits col s-1 from panel = H_s; 4-way K split + reduce
        if (s >= 1) {
            f32x4 lacc = {0.f, 0.f, 0.f, 0.f};
#pragma unroll
            for (int kk = 0; kk < 8; ++kk) {
                int k = w * 256 + kk * 32 + l4 * 8;
                bf16x8 af = *(const bf16x8*)(hbp + ((2 * k) ^ hs2));
                bf16x8 bf = *(const bf16x8*)(wo + k);
                lacc = __builtin_amdgcn_mfma_f32_16x16x32_bf16(af, bf, lacc, 0, 0, 0);
            }
#pragma unroll
            for (int j = 0; j < 4; ++j) red[tid * 5 + j] = lacc[j];
            __syncthreads();
            if (w == 0) {
                int growb = r0 + lrg * 16 + l4 * 4;
#pragma unroll
                for (int j = 0; j < 4; ++j) {
                    float ssum = red[(0 * 64 + lane) * 5 + j] + red[(64 + lane) * 5 + j]
                               + red[(128 + lane) * 5 + j] + red[(192 + lane) * 5 + j];
                    logits[((size_t)(growb + j) * L_ + (s - 1)) * V_ + vcol0 + l15] = ssum;
                }
            }
        }
        __syncthreads();   // panel/red safe to overwrite next iteration
    }
}

extern "C" void kernel_launch(void* const* d_in, const int* in_sizes, int n_in,
                              void* d_out, int out_size, void* d_ws, size_t ws_size,
                              hipStream_t stream)
{
    const int*   x   = (const int*)d_in[0];
    const float* hid = (const float*)d_in[1];
    const float* emb = (const float*)d_in[2];
    const float* We  = (const float*)d_in[3];
    const float* Wh  = (const float*)d_in[4];
    const float* Wo  = (const float*)d_in[5];

    float* logits  = (float*)d_out;                       // [B][L][V] f32
    float* final_h = logits + (size_t)B_ * L_ * V_;       // [B][H] f32

    char* ws = (char*)d_ws;
    float*  proj = (float*)(ws);                          // 1 MB   f32 [V][H]
    ushort* WhT  = (ushort*)(ws + (1u << 20));            // 2 MB   bf16 [H][H]^T
    ushort* WoT  = (ushort*)(ws + 3u * (1u << 20));       // 0.5 MB bf16 [V][H]^T
    u32*    ring = (u32*)(ws + 3u * (1u << 20) + (1u << 19)); // 2 MB u32 2x[B][H]

    const int RN = 2 * B_ * H_;   // ring words
    // prep (stream-ordered): invalidate ring tags EVERY launch (graph replay!)
    k_zero<<<dim3(RN / 256), 256, 0, stream>>>(ring, RN);
    k_transpose_bf16<<<dim3(16, 16), 256, 0, stream>>>(Wh, WhT, H_, H_);
    k_transpose_bf16<<<dim3(4, 16),  256, 0, stream>>>(Wo, WoT, H_, V_);
    k_pack0<<<dim3(B_ * H_ / 256), 256, 0, stream>>>(hid, ring, B_ * H_);  // H_0, tag 0
    k_proj<<<dim3(256, 4), 256, 0, stream>>>(emb, We, proj);

    // one persistent kernel: 512 scan steps + fused logits
    k_scan<<<dim3(256), 256, 0, stream>>>(x, proj, WhT, WoT, ring,
                                          logits, final_h);
}

// Round 9
// 2461.243 us; speedup vs baseline: 1.2224x; 1.2224x over previous
//
#include <hip/hip_runtime.h>
#include <hip/hip_bf16.h>
#include <math.h>

#define B_ 256
#define L_ 512
#define V_ 256
#define E_ 256
#define H_ 1024

typedef float  f32x4  __attribute__((ext_vector_type(4)));
typedef short  bf16x8 __attribute__((ext_vector_type(8)));
typedef unsigned int u32;
typedef unsigned char u8;

static __device__ __forceinline__ ushort f2bf(float v) {
    __hip_bfloat16 b = __float2bfloat16(v);
    return *reinterpret_cast<ushort*>(&b);
}

// fast tanh: 1 - 2/(exp(2z)+1); exact limits, ~1e-7 rel err
static __device__ __forceinline__ float ftanh(float z) {
    float e = __expf(2.f * z);
    return 1.f - 2.f / (e + 1.f);
}

// ---------- prep: transpose f32 [R][C] -> bf16 [C][R] ----------
__global__ void k_transpose_bf16(const float* __restrict__ in, ushort* __restrict__ out,
                                 int R, int C) {
    __shared__ float tile[64][65];
    int bx = blockIdx.x, by = blockIdx.y;
    int tid = threadIdx.x;
    int g = tid >> 6, l = tid & 63;
    for (int i = 0; i < 16; ++i) {
        int r = g * 16 + i;
        tile[r][l] = in[(size_t)(by * 64 + r) * C + bx * 64 + l];
    }
    __syncthreads();
    for (int i = 0; i < 16; ++i) {
        int c = g * 16 + i;
        out[(size_t)(bx * 64 + c) * R + by * 64 + l] = f2bf(tile[l][c]);
    }
}

__global__ void k_zero(u32* __restrict__ p, int n) {
    int i = blockIdx.x * blockDim.x + threadIdx.x;
    if (i < n) p[i] = 0u;
}

// pack H_0 (f32 [256][1024]) as bf16 into ringA slot0 (rows 0-127) / ringB slot0 (128-255)
__global__ void k_pack_h0(const float* __restrict__ hid, ushort* __restrict__ ringA,
                          ushort* __restrict__ ringB) {
    int i = blockIdx.x * blockDim.x + threadIdx.x;   // 0 .. 256*1024
    ushort v = f2bf(hid[i]);
    int half = i >> 17;                               // rows 0-127 vs 128-255
    int off = i & 131071;
    if (half == 0) ringA[off] = v; else ringB[off] = v;
}

__global__ void k_proj(const float* __restrict__ emb, const float* __restrict__ We,
                       float* __restrict__ proj) {
    __shared__ float er[E_];
    int t = blockIdx.x;
    int h = blockIdx.y * 256 + threadIdx.x;
    er[threadIdx.x] = emb[t * E_ + threadIdx.x];
    __syncthreads();
    float acc = 0.f;
#pragma unroll 8
    for (int e = 0; e < E_; ++e) acc += er[e] * We[(size_t)e * H_ + h];
    proj[(size_t)t * H_ + h] = acc;
}

// ---------- persistent scan: A/B half-batch temporal pipeline ----------
// 256 blocks, 1/CU (100KB LDS). Block (rg=bid&7, cg=bid>>3) owns a 16x32 tile in
// BOTH batch halves: half-X rows [X*128+rg*16,+16), cols [cg*32,+32); same W_h^T
// slice (LDS) serves both. Phases alternate halves; per phase: poll half-X flags
// (set a full phase earlier), issue X's 32KB stage, store the OTHER half's
// deferred outputs (H tile + drain + flag, logits tile) under the stage flight,
// drain, then waves 0-1 compute H^X_{s+1} (kept in stile) while waves 2-3
// compute logits partials (red). Transport = R3-proven sc0 sc1 + drain-then-flag,
// per-producer flags, blockIdx-only mapping. Reads hit ring X, writes ring X'.
__global__ __launch_bounds__(256, 1) void k_scan(
    const int* __restrict__ xs, const float* __restrict__ proj,
    const ushort* __restrict__ WhT, const ushort* __restrict__ WoT,
    ushort* __restrict__ ringA, ushort* __restrict__ ringB,
    float* __restrict__ logits, float* __restrict__ final_h,
    u8* __restrict__ flags)
{
    __shared__ ushort lds_w[32 * 1024];   // W_h^T cols [c0,+32), swizzled (64KB)
    __shared__ ushort panel[16 * 1024];   // half-X rows slice (32KB), swizzled
    __shared__ float  red[2][16][17];     // logits K-half partials (2.2KB)
    __shared__ ushort stile[16 * 32];     // pending H tile (1KB)

    int tid = threadIdx.x;
    int w = tid >> 6, lane = tid & 63;
    int l15 = lane & 15, l4 = lane >> 4;
    int bid = blockIdx.x;
    int rg = bid & 7, cg = bid >> 3;
    int c0 = cg * 32;

    // --- preload W slice once (drained by first phase's vmcnt(0))
    {
        const char* wsrc = (const char*)(WhT + (size_t)c0 * H_);
        char* wd = (char*)lds_w;
        for (int i = 0; i < 16; ++i) {
            int chunk = (w * 16 + i) * 1024;
            int o = chunk + lane * 16;
            int row = o >> 11, b = o & 2047;
            int so = row * 2048 + (b ^ ((row & 7) << 4));
            __builtin_amdgcn_global_load_lds(
                (const __attribute__((address_space(1))) void*)(wsrc + so),
                (__attribute__((address_space(3))) void*)(wd + chunk), 16, 0, 0);
        }
    }

    int as = (l15 & 7) << 4;     // row swizzle for panel row l15 AND lds_w row w*16+l15 (16 ≡ 0 mod 8)
    const char* wa = (const char*)lds_w + (size_t)((w & 1) * 16 + l15) * 2048;  // A B-frag (w<2)
    int vcol0 = (cg & 15) * 16;                                  // B vocab tile (cg<16)
    const ushort* wo = WoT + (size_t)(vcol0 + l15) * H_;

    for (int p = 0; p <= 2 * L_ + 2; ++p) {
        int hx = p & 1, s = p >> 1;
        int px = (p - 1) & 1, ps = (p - 1) >> 1;      // phase p-1 meta (valid for p>=1)
        bool doStage = (p <= 2 * L_ + 1);
        bool doPoll = doStage && (s >= 1);

        ushort* ringR = hx ? ringB : ringA;

        // --- 1. poll half-X producer flags (32 lanes <-> 32 producer blocks)
        if (w == 0 && doPoll) {
            const u8* fp = flags + ((size_t)(hx * 8 + rg) * 513 + s) * 32 + lane;
            u32 v = 1u;
            while (true) {
                if (lane < 32)
                    asm volatile("global_load_ubyte %0, %1, off sc0 sc1\n\t"
                                 "s_waitcnt vmcnt(0)" : "=v"(v) : "v"(fp) : "memory");
                if (__ballot(v != 0u) == ~0ull) break;
            }
        }
        __syncthreads();

        // --- 2. issue stage loads for H^X_s (32KB; fly under step 3)
        f32x4 tv[8];
        if (doStage) {
            const char* hsrc = (const char*)(ringR + (size_t)(s & 1) * 128 * H_
                                             + (size_t)(rg * 16) * H_) + tid * 16;
#pragma unroll
            for (int i = 0; i < 8; ++i)
                asm volatile("global_load_dwordx4 %0, %1, off sc0 sc1"
                             : "=v"(tv[i]) : "v"(hsrc + i * 4096) : "memory");
        }

        // --- 3. deferred stores of phase p-1 outputs (other half)
        if (p >= 1) {
            if (w == 0 && ps < L_) {          // H^px_{ps+1}: 64 lanes x 16B from stile
                ushort* ringW = px ? ringB : ringA;
                int r = lane >> 2, seg = lane & 3;
                f32x4 d = *(const f32x4*)&stile[r * 32 + seg * 8];
                char* dst = (char*)(ringW + (size_t)((ps + 1) & 1) * 128 * H_
                                    + (size_t)(rg * 16 + r) * H_ + c0 + seg * 8);
                asm volatile("global_store_dwordx4 %0, %1, off sc0 sc1"
                             :: "v"(dst), "v"(d) : "memory");
                asm volatile("s_waitcnt vmcnt(0)" ::: "memory");   // data at L3
                if (lane == 0) {
                    u8* fdst = flags + ((size_t)(px * 8 + rg) * 513 + (ps + 1)) * 32 + cg;
                    u32 one = 1u;
                    asm volatile("global_store_byte %0, %1, off sc0 sc1"
                                 :: "v"(fdst), "v"(one) : "memory");
                }
            }
            if (w == 2 && ps >= 1 && cg < 16) {   // logits^px col ps-1 from red
                int r = lane >> 2, c4 = (lane & 3) * 4;
                f32x4 o;
#pragma unroll
                for (int j = 0; j < 4; ++j) o[j] = red[0][r][c4 + j] + red[1][r][c4 + j];
                int grow = px * 128 + rg * 16 + r;
                *(f32x4*)&logits[((size_t)grow * L_ + (ps - 1)) * V_ + vcol0 + c4] = o;
            }
        }

        // --- pv gather for this phase's A compute (read-only, L2-warm)
        float pv[4];
        if (w < 2 && doStage && s < L_) {
#pragma unroll
            for (int j = 0; j < 4; ++j) {
                int grow = hx * 128 + rg * 16 + l4 * 4 + j;
                pv[j] = proj[(size_t)xs[grow * L_ + s] * H_ + c0 + w * 16 + l15];
            }
        }

        // --- 4. drain stage, swizzled panel write
        if (doStage) {
            asm volatile("s_waitcnt vmcnt(0)" ::: "memory");
#pragma unroll
            for (int i = 0; i < 8; ++i) {
                int o = i * 4096 + tid * 16;
                int row = o >> 11, b = o & 2047;
                *(f32x4*)((char*)panel + row * 2048 + (b ^ ((row & 7) << 4))) = tv[i];
            }
        }
        __syncthreads();   // panel = H^X_s

        // --- 5a. A compute (waves 0-1): H^X_{s+1} tile -> stile (stored next phase)
        if (w < 2 && doStage && s < L_) {
            const char* ha = (const char*)panel + l15 * 2048;
            f32x4 acc0 = {0.f,0.f,0.f,0.f}, acc1 = {0.f,0.f,0.f,0.f};
#pragma unroll
            for (int kk = 0; kk < 32; kk += 2) {
                int kb0 = (kk * 32 + l4 * 8) * 2;
                int kb1 = ((kk + 1) * 32 + l4 * 8) * 2;
                bf16x8 af0 = *(const bf16x8*)(ha + (kb0 ^ as));
                bf16x8 bf0 = *(const bf16x8*)(wa + (kb0 ^ as));
                bf16x8 af1 = *(const bf16x8*)(ha + (kb1 ^ as));
                bf16x8 bf1 = *(const bf16x8*)(wa + (kb1 ^ as));
                acc0 = __builtin_amdgcn_mfma_f32_16x16x32_bf16(af0, bf0, acc0, 0, 0, 0);
                acc1 = __builtin_amdgcn_mfma_f32_16x16x32_bf16(af1, bf1, acc1, 0, 0, 0);
            }
#pragma unroll
            for (int j = 0; j < 4; ++j) {
                int lrow = l4 * 4 + j;
                float hv = ftanh((acc0[j] + acc1[j]) + pv[j]);
                stile[lrow * 32 + w * 16 + l15] = f2bf(hv);
                if (s == L_ - 1) {
                    int grow = hx * 128 + rg * 16 + lrow;
                    final_h[(size_t)grow * H_ + c0 + w * 16 + l15] = hv;
                }
            }
        }

        // --- 5b. B compute (waves 2-3, cg<16): logits^X col s-1 partials -> red
        if (w >= 2 && doStage && s >= 1 && cg < 16) {
            const char* ha = (const char*)panel + l15 * 2048;
            int kh = w - 2;
            f32x4 acc0 = {0.f,0.f,0.f,0.f}, acc1 = {0.f,0.f,0.f,0.f};
#pragma unroll
            for (int kk = 0; kk < 16; kk += 2) {
                int k0 = kh * 512 + kk * 32 + l4 * 8;
                int k1 = k0 + 32;
                bf16x8 a0 = *(const bf16x8*)(ha + ((2 * k0) ^ as));
                bf16x8 b0 = *(const bf16x8*)(wo + k0);
                bf16x8 a1 = *(const bf16x8*)(ha + ((2 * k1) ^ as));
                bf16x8 b1 = *(const bf16x8*)(wo + k1);
                acc0 = __builtin_amdgcn_mfma_f32_16x16x32_bf16(a0, b0, acc0, 0, 0, 0);
                acc1 = __builtin_amdgcn_mfma_f32_16x16x32_bf16(a1, b1, acc1, 0, 0, 0);
            }
#pragma unroll
            for (int j = 0; j < 4; ++j) red[kh][l4 * 4 + j][l15] = acc0[j] + acc1[j];
        }
        __syncthreads();   // stile/red complete; panel free for next phase
    }
}

extern "C" void kernel_launch(void* const* d_in, const int* in_sizes, int n_in,
                              void* d_out, int out_size, void* d_ws, size_t ws_size,
                              hipStream_t stream)
{
    const int*   x   = (const int*)d_in[0];
    const float* hid = (const float*)d_in[1];
    const float* emb = (const float*)d_in[2];
    const float* We  = (const float*)d_in[3];
    const float* Wh  = (const float*)d_in[4];
    const float* Wo  = (const float*)d_in[5];

    float* logits  = (float*)d_out;                       // [B][L][V] f32
    float* final_h = logits + (size_t)B_ * L_ * V_;       // [B][H] f32

    char* ws = (char*)d_ws;
    float*  proj  = (float*)(ws);                                 // 1 MB   f32 [V][H]
    ushort* WhT   = (ushort*)(ws + (1u << 20));                   // 2 MB   bf16 [H][H]^T
    ushort* WoT   = (ushort*)(ws + 3u * (1u << 20));              // 0.5 MB bf16 [V][H]^T
    ushort* ringA = (ushort*)(ws + 3u * (1u << 20) + (1u << 19)); // 512 KB 2x[128][1024]
    ushort* ringB = (ushort*)(ws + 4u * (1u << 20));              // 512 KB 2x[128][1024]
    u8*     flags = (u8*)(ws + 4u * (1u << 20) + (1u << 19));     // 257 KB [2][8][513][32]

    const int FN = 2 * 8 * 513 * 32 / 4;   // flag words to zero
    k_zero<<<dim3((FN + 255) / 256), 256, 0, stream>>>((u32*)flags, FN);
    k_transpose_bf16<<<dim3(16, 16), 256, 0, stream>>>(Wh, WhT, H_, H_);
    k_transpose_bf16<<<dim3(4, 16),  256, 0, stream>>>(Wo, WoT, H_, V_);
    k_pack_h0<<<dim3(B_ * H_ / 256), 256, 0, stream>>>(hid, ringA, ringB);
    k_proj<<<dim3(256, 4), 256, 0, stream>>>(emb, We, proj);

    // one persistent kernel: 2x513 pipelined phases + 1 drain phase
    k_scan<<<dim3(256), 256, 0, stream>>>(x, proj, WhT, WoT, ringA, ringB,
                                          logits, final_h, flags);
}